// Round 9
// baseline (6395.739 us; speedup 1.0000x reference)
//
#include <hip/hip_runtime.h>
#include <math.h>

#define BATCH 128
#define CCH 5
#define SEQ 512
#define UNITS 256
#define RU 512

#define ENC_N 33554432   // BATCH*SEQ*RU floats

__device__ __forceinline__ float sigmoidf_(float v) {
    return 1.0f / (1.0f + __expf(-v));
}
__device__ __forceinline__ float tanhf_(float v) {
    float e = __expf(2.0f * v);
    return 1.0f - 2.0f / (e + 1.0f);
}
__device__ __forceinline__ void astoref(float* p, float v) {
    __hip_atomic_store(p, v, __ATOMIC_RELAXED, __HIP_MEMORY_SCOPE_AGENT);
}
__device__ __forceinline__ void astorei(int* p, int v) {
    __hip_atomic_store(p, v, __ATOMIC_RELAXED, __HIP_MEMORY_SCOPE_AGENT);
}
__device__ __forceinline__ unsigned long long aloadu64(const unsigned long long* p) {
    return __hip_atomic_load(p, __ATOMIC_RELAXED, __HIP_MEMORY_SCOPE_AGENT);
}
__device__ __forceinline__ int aloadi(const int* p) {
    return __hip_atomic_load(p, __ATOMIC_RELAXED, __HIP_MEMORY_SCOPE_AGENT);
}

// ---------------------------------------------------------------------------
// Encoder: 256 blocks = dir(2) x tile(16; 8 batches) x slice(8; 32 units).
// 3 barriers/step: B1 (h ready) -> z-partials (packed float2 zp) -> B2 ->
// stage-A (1024-thread slot reduction + x@Wk) -> B2b -> stage-B (256-thread
// gates) -> mini-sync (4 waves, vmcnt+LDS ctr) -> flag. hL double-buffered.
// ---------------------------------------------------------------------------
__global__ __attribute__((amdgpu_flat_work_group_size(1024, 1024),
                          amdgpu_waves_per_eu(4, 4)))
void encoder_kernel(const float* __restrict__ x,
                    const float* __restrict__ Wf_k, const float* __restrict__ Wf_r,
                    const float* __restrict__ bf,
                    const float* __restrict__ Wb_k, const float* __restrict__ Wb_r,
                    const float* __restrict__ bb,
                    float* __restrict__ enc, float* __restrict__ h_ex,
                    int* __restrict__ flags)
{
    const int bid  = blockIdx.x;
    const int dir  = bid >> 7;
    const int tile = (bid >> 3) & 15;
    const int jsl  = bid & 7;
    const int grp  = dir * 16 + tile;
    const int bg0  = tile * 8;
    const float* __restrict__ Wk   = dir ? Wb_k : Wf_k;
    const float* __restrict__ Wr   = dir ? Wb_r : Wf_r;
    const float* __restrict__ bias = dir ? bb : bf;
    const int tid  = threadIdx.x;
    const int wv   = tid >> 6;
    const int lane = tid & 63;
    const int g0 = ((lane >> 5) << 8) + jsl * 32 + (lane & 31);

    __shared__ float2 zpP[16][8][64];               // 64 KB
    __shared__ float __align__(16) hLe[2][8][260];  // 16.6 KB (dbuf, +4 pad)
    __shared__ float zred[8][128];                  // 4 KB
    __shared__ float WkL[5][128];
    __shared__ float biasL[128];
    __shared__ unsigned char mL[8][SEQ];            // 4 KB
    __shared__ float xLe[8][8];
    __shared__ int msync;

    // ---- one-time staging ----
    for (int i = tid; i < 2 * 8 * 260; i += 1024) ((float*)hLe)[i] = 0.0f;
    if (tid == 0) msync = 0;
    if (tid < 128) biasL[tid] = bias[((tid >> 5) << 8) + jsl * 32 + (tid & 31)];
    if (tid >= 128 && tid < 768) {
        int i = tid - 128, c = i >> 7, cl = i & 127;
        WkL[c][cl] = Wk[c * 1024 + ((cl >> 5) << 8) + jsl * 32 + (cl & 31)];
    }
    for (int i = tid; i < 8 * SEQ; i += 1024) {
        int b = i >> 9, tt = i & (SEQ - 1);
        mL[b][tt] = (x[((size_t)((bg0 + b) * CCH) * SEQ + tt) * 3 + 2] != 0.0f) ? 1 : 0;
    }
    // weights -> registers (pinned): rows 16*wv..+15, cols g0 and g0+512
    float wr0[16], wr1[16];
    {
        const float* wbase = Wr + (size_t)(wv * 16) * 1024 + g0;
        #pragma unroll
        for (int r = 0; r < 16; ++r) {
            wr0[r] = wbase[(size_t)r * 1024];
            wr1[r] = wbase[(size_t)r * 1024 + 512];
        }
        #pragma unroll
        for (int r = 0; r < 16; ++r)
            asm volatile("" : "+v"(wr0[r]), "+v"(wr1[r]));
    }
    float creg = 0.0f;
    __syncthreads();

    for (int t = 0; t < SEQ; ++t) {
        const int cur = t & 1;
        const int ts = dir ? (SEQ - 1 - t) : t;
        if (t > 0 && wv < 8) {
            const int* fp = &flags[(grp * 8 + wv) * 32];
            if (lane == 0) {
                int guard = 0;
                while (aloadi(fp) < t && guard < (1 << 26)) {
                    __builtin_amdgcn_s_sleep(1); ++guard;
                }
            }
            int b = lane >> 3, u = wv * 32 + (lane & 7) * 4;
            const unsigned long long* hsrc = (const unsigned long long*)
                &h_ex[(size_t)(dir * 2 + ((t - 1) & 1)) * (BATCH * UNITS)
                      + (size_t)(bg0 + b) * UNITS + u];
            unsigned long long v0 = aloadu64(hsrc);
            unsigned long long v1 = aloadu64(hsrc + 1);
            *(unsigned long long*)&hLe[cur][b][u]     = v0;
            *(unsigned long long*)&hLe[cur][b][u + 2] = v1;
        }
        if (tid >= 960 && tid < 1000) {  // wave 15: x_t for the 8 batches
            int i = tid - 960, b = i / 5, c = i - b * 5;
            xLe[b][c] = x[((size_t)((bg0 + b) * CCH + c) * SEQ + ts) * 3];
        }
        __syncthreads();   // B1

        // z partials: 8 batches x (16 rows x 2 cols) per lane
        float accA[8], accB[8];
        #pragma unroll
        for (int b = 0; b < 8; ++b) {
            float a0 = 0.f, a1 = 0.f;
            const float4* hp = (const float4*)&hLe[cur][b][wv * 16];
            #pragma unroll
            for (int q = 0; q < 4; ++q) {
                float4 h4 = hp[q];
                a0 = fmaf(h4.x, wr0[4*q+0], a0); a1 = fmaf(h4.x, wr1[4*q+0], a1);
                a0 = fmaf(h4.y, wr0[4*q+1], a0); a1 = fmaf(h4.y, wr1[4*q+1], a1);
                a0 = fmaf(h4.z, wr0[4*q+2], a0); a1 = fmaf(h4.z, wr1[4*q+2], a1);
                a0 = fmaf(h4.w, wr0[4*q+3], a0); a1 = fmaf(h4.w, wr1[4*q+3], a1);
            }
            accA[b] = a0; accB[b] = a1;
        }
        #pragma unroll
        for (int b = 0; b < 8; ++b)
            zpP[wv][b][lane] = make_float2(accA[b], accB[b]);
        __syncthreads();   // B2

        // stage-A: 1024 threads, one (b, cl) each: bias + 16 slots + x@Wk
        {
            int b = tid >> 7, cl = tid & 127;
            int gate = cl >> 5, u = cl & 31;
            int lane_r = ((gate & 1) << 5) | u;
            int comp = gate >> 1;
            const float* zf = (const float*)zpP + b * 128 + lane_r * 2 + comp;
            float sum = biasL[cl];
            #pragma unroll
            for (int s = 0; s < 16; ++s) sum += zf[s * 1024];
            #pragma unroll
            for (int c = 0; c < 5; ++c) sum = fmaf(xLe[b][c], WkL[c][cl], sum);
            zred[b][cl] = sum;
        }
        __syncthreads();   // B2b

        if (tid < 256) {   // stage-B: gates + mask + publish
            int b = tid >> 5, u = tid & 31;
            float zi = zred[b][u];
            float zf_ = zred[b][32 + u];
            float zg = zred[b][64 + u];
            float zo = zred[b][96 + u];
            float cn = sigmoidf_(zf_) * creg + sigmoidf_(zi) * tanhf_(zg);
            float hn = sigmoidf_(zo) * tanhf_(cn);
            float hprev = hLe[cur][b][jsl * 32 + u];
            float h2 = mL[b][ts] ? hn : hprev;
            float c2 = mL[b][ts] ? cn : creg;
            creg = c2;
            astoref(&h_ex[(size_t)(dir * 2 + (t & 1)) * (BATCH * UNITS)
                          + (size_t)(bg0 + b) * UNITS + jsl * 32 + u], h2);
            enc[((size_t)(bg0 + b) * SEQ + ts) * RU + dir * UNITS + jsl * 32 + u] = h2;
            if (lane == 0) {
                asm volatile("s_waitcnt vmcnt(0)" ::: "memory");
                __hip_atomic_fetch_add(&msync, 1, __ATOMIC_RELAXED,
                                       __HIP_MEMORY_SCOPE_WORKGROUP);
            }
            if (tid == 0) {
                int target = 4 * (t + 1), guard = 0;
                while (__hip_atomic_load(&msync, __ATOMIC_RELAXED,
                                         __HIP_MEMORY_SCOPE_WORKGROUP) < target &&
                       guard < (1 << 26)) ++guard;
                astorei(&flags[(grp * 8 + jsl) * 32], t + 1);
            }
        }
        // no trailing barrier: next-iteration B1 provides the ordering
        // (hLe double-buffered; zpP/zred reads all complete before B2b)
    }
}

// ---------------------------------------------------------------------------
// Attention precompute (alpha constant over decoder time). One block/batch.
// ---------------------------------------------------------------------------
__global__ __launch_bounds__(256)
void attn_kernel(const float* __restrict__ enc,
                 const float* __restrict__ W_attn, const float* __restrict__ b_attn,
                 const float* __restrict__ W_dense, const float* __restrict__ b_dense,
                 const float* __restrict__ x,
                 float* __restrict__ attn_ws, float* __restrict__ hidden_ws,
                 float* __restrict__ xbuf, float* __restrict__ xconst)
{
    const int b = blockIdx.x;
    const int tid = threadIdx.x;
    const int lane = tid & 63;
    const int wv = tid >> 6;

    __shared__ float WeL[RU];
    __shared__ float scoresL[SEQ];
    __shared__ float red[256];
    __shared__ float attnL[RU];

    WeL[tid]       = W_attn[CCH + tid];
    WeL[tid + 256] = W_attn[CCH + tid + 256];
    __syncthreads();

    const float* __restrict__ encb = enc + (size_t)b * SEQ * RU;
    const float batt = b_attn[0];

    for (int s = wv; s < SEQ; s += 4) {
        const float* row = encb + (size_t)s * RU;
        float p = 0.0f;
        #pragma unroll
        for (int i = 0; i < 8; ++i) {
            int d = lane * 8 + i;
            p = fmaf(row[d], WeL[d], p);
        }
        #pragma unroll
        for (int o = 32; o; o >>= 1) p += __shfl_xor(p, o);
        if (lane == 0) scoresL[s] = p + batt;
    }
    __syncthreads();

    float m = fmaxf(scoresL[tid], scoresL[tid + 256]);
    red[tid] = m;
    __syncthreads();
    for (int st = 128; st; st >>= 1) {
        if (tid < st) red[tid] = fmaxf(red[tid], red[tid + st]);
        __syncthreads();
    }
    const float mx = red[0];
    __syncthreads();
    float e0 = __expf(scoresL[tid] - mx);
    float e1 = __expf(scoresL[tid + 256] - mx);
    red[tid] = e0 + e1;
    __syncthreads();
    for (int st = 128; st; st >>= 1) {
        if (tid < st) red[tid] += red[tid + st];
        __syncthreads();
    }
    const float sinv = 1.0f / red[0];
    __syncthreads();
    scoresL[tid]       = e0 * sinv;
    scoresL[tid + 256] = e1 * sinv;
    __syncthreads();

    float a0 = 0.0f, a1 = 0.0f;
    for (int s = 0; s < SEQ; ++s) {
        float al = scoresL[s];
        a0 = fmaf(al, encb[(size_t)s * RU + tid], a0);
        a1 = fmaf(al, encb[(size_t)s * RU + tid + 256], a1);
    }
    attn_ws[(size_t)b * RU + tid]       = a0;
    attn_ws[(size_t)b * RU + tid + 256] = a1;
    attnL[tid] = a0;
    attnL[tid + 256] = a1;
    hidden_ws[(size_t)b * RU + tid]       = encb[(size_t)(SEQ - 1) * RU + tid];
    hidden_ws[(size_t)b * RU + tid + 256] = encb[(size_t)(SEQ - 1) * RU + tid + 256];
    if (tid < CCH) xbuf[b * CCH + tid] = x[((size_t)(b * CCH + tid) * SEQ + 0) * 3];
    __syncthreads();

    if (tid < CCH) {
        float acc = b_dense[tid];
        for (int d = 0; d < RU; ++d)
            acc = fmaf(attnL[d], W_dense[(RU + d) * CCH + tid], acc);
        xconst[b * CCH + tid] = acc;
    }
}

// ---------------------------------------------------------------------------
// Decoder: 256 blocks = tile(16; 8 batches) x slice(16; 32 units).
// Same 3-barrier step; x_t dense-reduce overlapped with z-partials (it only
// needs h); out[] store after the flag post (off the drain path).
// ---------------------------------------------------------------------------
__global__ __attribute__((amdgpu_flat_work_group_size(1024, 1024),
                          amdgpu_waves_per_eu(4, 4)))
void decoder_kernel(const float* __restrict__ Wd_k, const float* __restrict__ Wd_r,
                    const float* __restrict__ bd,
                    const float* __restrict__ W_dense,
                    const float* __restrict__ attn_ws, const float* __restrict__ hidden_ws,
                    const float* __restrict__ xbuf, const float* __restrict__ xconst,
                    float* __restrict__ h_ex, int* __restrict__ flags,
                    float* __restrict__ out)
{
    const int bid  = blockIdx.x;
    const int tile = bid >> 4;
    const int jsl  = bid & 15;
    const int bg0  = tile * 8;
    const int tid  = threadIdx.x;
    const int wv   = tid >> 6;
    const int lane = tid & 63;
    const int g0 = ((lane >> 5) << 9) + jsl * 32 + (lane & 31);

    __shared__ float2 zpP[16][8][64];               // 64 KB
    __shared__ float __align__(16) hLd[2][8][516];  // 33 KB (dbuf, +4 pad)
    __shared__ float zred[8][128];                  // 4 KB
    __shared__ float WdL[RU * CCH];                 // 10 KB
    __shared__ float WkL[5][128];                   // 2.5 KB
    __shared__ float biasL[128];
    __shared__ float attL[8][32];
    __shared__ float xL[8][8], xcL[8][8];
    __shared__ int msync;

    // ---- one-time staging ----
    for (int i = tid; i < RU * CCH; i += 1024) WdL[i] = W_dense[i];
    if (tid == 0) msync = 0;
    if (tid < 128) biasL[tid] = bd[((tid >> 5) << 9) + jsl * 32 + (tid & 31)];
    if (tid >= 128 && tid < 768) {
        int i = tid - 128, c = i >> 7, cl = i & 127;
        WkL[c][cl] = Wd_k[c * 2048 + ((cl >> 5) << 9) + jsl * 32 + (cl & 31)];
    }
    if (tid < 256) {
        int b = tid >> 5, u = tid & 31;
        attL[b][u] = attn_ws[(size_t)(bg0 + b) * RU + jsl * 32 + u];
    }
    if (tid < 64) {
        int b = tid >> 3, c = tid & 7;
        if (c < 5) {
            xL[b][c]  = xbuf[(bg0 + b) * CCH + c];
            xcL[b][c] = xconst[(bg0 + b) * CCH + c];
        }
    }
    {   // t=0 h from hidden_ws
        int f = tid * 4, b = f >> 9, u = f & (RU - 1);
        float4 v = *(const float4*)&hidden_ws[(size_t)(bg0 + b) * RU + u];
        *(float4*)&hLd[0][b][u] = v;
    }
    // weights -> registers (pinned): rows 32*wv..+31, cols g0 and g0+1024
    float wr0[32], wr1[32];
    {
        const float* wbase = Wd_r + (size_t)(wv * 32) * 2048 + g0;
        #pragma unroll
        for (int r = 0; r < 32; ++r) {
            wr0[r] = wbase[(size_t)r * 2048];
            wr1[r] = wbase[(size_t)r * 2048 + 1024];
        }
        #pragma unroll
        for (int r = 0; r < 32; ++r)
            asm volatile("" : "+v"(wr0[r]), "+v"(wr1[r]));
    }
    __syncthreads();

    for (int t = 0; t < SEQ - 1; ++t) {
        const int cur = t & 1;
        if (t > 0) {
            const int* fp = &flags[(tile * 16 + wv) * 32];
            if (lane == 0) {
                int guard = 0;
                while (aloadi(fp) < t && guard < (1 << 26)) {
                    __builtin_amdgcn_s_sleep(1); ++guard;
                }
            }
            int b = lane >> 3, u = wv * 32 + (lane & 7) * 4;
            const unsigned long long* hsrc = (const unsigned long long*)
                &h_ex[(size_t)((t - 1) & 1) * (BATCH * RU)
                      + (size_t)(bg0 + b) * RU + u];
            unsigned long long v0 = aloadu64(hsrc);
            unsigned long long v1 = aloadu64(hsrc + 1);
            *(unsigned long long*)&hLd[cur][b][u]     = v0;
            *(unsigned long long*)&hLd[cur][b][u + 2] = v1;
        }
        __syncthreads();   // B1

        // z partials: 8 batches x (32 rows x 2 cols) per lane
        float accA[8], accB[8];
        #pragma unroll
        for (int b = 0; b < 8; ++b) {
            float a0 = 0.f, a1 = 0.f;
            const float4* hp = (const float4*)&hLd[cur][b][wv * 32];
            #pragma unroll
            for (int q = 0; q < 8; ++q) {
                float4 h4 = hp[q];
                a0 = fmaf(h4.x, wr0[4*q+0], a0); a1 = fmaf(h4.x, wr1[4*q+0], a1);
                a0 = fmaf(h4.y, wr0[4*q+1], a0); a1 = fmaf(h4.y, wr1[4*q+1], a1);
                a0 = fmaf(h4.z, wr0[4*q+2], a0); a1 = fmaf(h4.z, wr1[4*q+2], a1);
                a0 = fmaf(h4.w, wr0[4*q+3], a0); a1 = fmaf(h4.w, wr1[4*q+3], a1);
            }
            accA[b] = a0; accB[b] = a1;
        }
        #pragma unroll
        for (int b = 0; b < 8; ++b)
            zpP[wv][b][lane] = make_float2(accA[b], accB[b]);

        // x_t dense-reduce (needs only h): overlapped with z-partial phase
        if (t > 0) {
            for (int it = wv; it < 40; it += 16) {
                int bb = it / 5, c = it - bb * 5;
                float p = 0.f;
                #pragma unroll
                for (int q = 0; q < 8; ++q) {
                    int uu = lane + (q << 6);
                    p = fmaf(hLd[cur][bb][uu], WdL[uu * CCH + c], p);
                }
                #pragma unroll
                for (int o = 32; o; o >>= 1) p += __shfl_xor(p, o);
                if (lane == 0) xL[bb][c] = p + xcL[bb][c];
            }
        }
        __syncthreads();   // B2

        // stage-A: 1024 threads, one (b, cl) each: bias + 16 slots + x@Wk
        {
            int b = tid >> 7, cl = tid & 127;
            int gate = cl >> 5, u = cl & 31;
            int lane_r = ((gate & 1) << 5) | u;
            int comp = gate >> 1;
            const float* zf = (const float*)zpP + b * 128 + lane_r * 2 + comp;
            float sum = biasL[cl];
            #pragma unroll
            for (int s = 0; s < 16; ++s) sum += zf[s * 1024];
            #pragma unroll
            for (int c = 0; c < 5; ++c) sum = fmaf(xL[b][c], WkL[c][cl], sum);
            zred[b][cl] = sum;
        }
        __syncthreads();   // B2b

        if (tid < 256) {   // stage-B: gates + publish h
            int b = tid >> 5, u = tid & 31;
            float zi = zred[b][u];
            float zf_ = zred[b][32 + u];
            float zg = zred[b][64 + u];
            float zo = zred[b][96 + u];
            float cn = sigmoidf_(zf_) * attL[b][u] + sigmoidf_(zi) * tanhf_(zg);
            float hn = sigmoidf_(zo) * tanhf_(cn);
            astoref(&h_ex[(size_t)(t & 1) * (BATCH * RU)
                          + (size_t)(bg0 + b) * RU + jsl * 32 + u], hn);
            if (lane == 0) {
                asm volatile("s_waitcnt vmcnt(0)" ::: "memory");
                __hip_atomic_fetch_add(&msync, 1, __ATOMIC_RELAXED,
                                       __HIP_MEMORY_SCOPE_WORKGROUP);
            }
            if (tid == 0) {
                int target = 4 * (t + 1), guard = 0;
                while (__hip_atomic_load(&msync, __ATOMIC_RELAXED,
                                         __HIP_MEMORY_SCOPE_WORKGROUP) < target &&
                       guard < (1 << 26)) ++guard;
                astorei(&flags[(tile * 16 + jsl) * 32], t + 1);
            }
        }
        // out-write after flag post (off the drain path)
        if (t > 0 && jsl == 0 && tid >= 256 && tid < 296) {
            int i = tid - 256, bb = i / 5, c = i - bb * 5;
            out[(size_t)((bg0 + bb) * CCH + c) * (SEQ - 1) + (t - 1)] = xL[bb][c];
        }
    }

    // ---- epilogue: t = 511 -> out[510] from h_511 ----
    {
        const int t = SEQ - 1;          // 511
        const int cur = t & 1;          // 1
        const int* fp = &flags[(tile * 16 + wv) * 32];
        if (lane == 0) {
            int guard = 0;
            while (aloadi(fp) < t && guard < (1 << 26)) {
                __builtin_amdgcn_s_sleep(1); ++guard;
            }
        }
        int b = lane >> 3, u = wv * 32 + (lane & 7) * 4;
        const unsigned long long* hsrc = (const unsigned long long*)
            &h_ex[(size_t)((t - 1) & 1) * (BATCH * RU)
                  + (size_t)(bg0 + b) * RU + u];
        unsigned long long v0 = aloadu64(hsrc);
        unsigned long long v1 = aloadu64(hsrc + 1);
        *(unsigned long long*)&hLd[cur][b][u]     = v0;
        *(unsigned long long*)&hLd[cur][b][u + 2] = v1;
        __syncthreads();
        if (jsl == 0) {
            for (int it = wv; it < 40; it += 16) {
                int bb = it / 5, c = it - bb * 5;
                float p = 0.f;
                #pragma unroll
                for (int q = 0; q < 8; ++q) {
                    int uu = lane + (q << 6);
                    p = fmaf(hLd[cur][bb][uu], WdL[uu * CCH + c], p);
                }
                #pragma unroll
                for (int o = 32; o; o >>= 1) p += __shfl_xor(p, o);
                if (lane == 0)
                    out[(size_t)((bg0 + bb) * CCH + c) * (SEQ - 1) + (t - 1)]
                        = p + xcL[bb][c];
            }
        }
    }
}

// ---------------------------------------------------------------------------
extern "C" void kernel_launch(void* const* d_in, const int* in_sizes, int n_in,
                              void* d_out, int out_size, void* d_ws, size_t ws_size,
                              hipStream_t stream)
{
    const float* x       = (const float*)d_in[0];
    const float* Wf_k    = (const float*)d_in[1];
    const float* Wf_r    = (const float*)d_in[2];
    const float* bf      = (const float*)d_in[3];
    const float* Wb_k    = (const float*)d_in[4];
    const float* Wb_r    = (const float*)d_in[5];
    const float* bb      = (const float*)d_in[6];
    const float* Wd_k    = (const float*)d_in[7];
    const float* Wd_r    = (const float*)d_in[8];
    const float* bd      = (const float*)d_in[9];
    const float* W_attn  = (const float*)d_in[10];
    const float* b_attn  = (const float*)d_in[11];
    const float* W_dense = (const float*)d_in[12];
    const float* b_dense = (const float*)d_in[13];
    float* out = (float*)d_out;

    float* ws = (float*)d_ws;
    // persistent (attn -> decoder) region after enc
    float* enc      = ws;                          // [0, ENC_N)
    float* attn_p   = ws + ENC_N;                  // 65536 floats
    float* hidden_p = ws + ENC_N + 65536;          // 65536 floats
    float* xbuf_p   = ws + ENC_N + 131072;         // 640
    float* xconst_p = ws + ENC_N + 131712;         // 640
    // encoder-phase overlays (dead before attn_kernel writes the same region)
    float* h_ex_e   = ws + ENC_N;                  // 4 x 128 x 256 = 131072 floats
    int*   flag_e   = (int*)(ws + ENC_N + 131072); // 32 grp x 8 x 32 = 8192 ints
    // decoder-phase overlays on dead enc region
    int*   flag_d   = (int*)ws;                    // 16 tile x 16 x 32 = 8192 ints
    float* h_ex_d   = ws + 8192;                   // 2 x 128 x 512 = 131072 floats

    hipMemsetAsync(flag_e, 0, 8192 * sizeof(int), stream);
    encoder_kernel<<<256, 1024, 0, stream>>>(x, Wf_k, Wf_r, bf, Wb_k, Wb_r, bb,
                                             enc, h_ex_e, flag_e);
    attn_kernel<<<BATCH, 256, 0, stream>>>(enc, W_attn, b_attn, W_dense, b_dense, x,
                                           attn_p, hidden_p, xbuf_p, xconst_p);
    hipMemsetAsync(flag_d, 0, 8192 * sizeof(int), stream);
    decoder_kernel<<<256, 1024, 0, stream>>>(Wd_k, Wd_r, bd, W_dense,
                                             attn_p, hidden_p, xbuf_p, xconst_p,
                                             h_ex_d, flag_d, out);
}

// Round 10
// 5598.938 us; speedup vs baseline: 1.1423x; 1.1423x over previous
//
#include <hip/hip_runtime.h>
#include <math.h>

#define BATCH 128
#define CCH 5
#define SEQ 512
#define UNITS 256
#define RU 512

#define ENC_N 33554432   // BATCH*SEQ*RU floats

typedef float v2f __attribute__((ext_vector_type(2)));

__device__ __forceinline__ float sigmoidf_(float v) {
    return 1.0f / (1.0f + __expf(-v));
}
__device__ __forceinline__ float tanhf_(float v) {
    float e = __expf(2.0f * v);
    return 1.0f - 2.0f / (e + 1.0f);
}
__device__ __forceinline__ void astoref(float* p, float v) {
    __hip_atomic_store(p, v, __ATOMIC_RELAXED, __HIP_MEMORY_SCOPE_AGENT);
}
__device__ __forceinline__ void astorei(int* p, int v) {
    __hip_atomic_store(p, v, __ATOMIC_RELAXED, __HIP_MEMORY_SCOPE_AGENT);
}
__device__ __forceinline__ unsigned long long aloadu64(const unsigned long long* p) {
    return __hip_atomic_load(p, __ATOMIC_RELAXED, __HIP_MEMORY_SCOPE_AGENT);
}
__device__ __forceinline__ int aloadi(const int* p) {
    return __hip_atomic_load(p, __ATOMIC_RELAXED, __HIP_MEMORY_SCOPE_AGENT);
}

// packed fp32 FMA, batch-pair in h2, column chosen from w2 via op_sel:
//   PK_LO: acc.{lo,hi} += h2.{lo,hi} * w2.lo   (column 0)
//   PK_HI: acc.{lo,hi} += h2.{lo,hi} * w2.hi   (column 1)
#define PK_LO(ACC, H2, W2) \
    asm("v_pk_fma_f32 %0, %1, %2, %0 op_sel:[0,0,0] op_sel_hi:[1,0,1]" \
        : "+v"(ACC) : "v"(H2), "v"(W2))
#define PK_HI(ACC, H2, W2) \
    asm("v_pk_fma_f32 %0, %1, %2, %0 op_sel:[0,1,0] op_sel_hi:[1,1,1]" \
        : "+v"(ACC) : "v"(H2), "v"(W2))

// ---------------------------------------------------------------------------
// Encoder: 256 blocks = dir(2) x tile(16; 8 batches) x slice(8; 32 units).
// h batch-paired in LDS; weights (16 rows x 2 cols)/lane; v_pk_fma_f32 core.
// Poll is slice-matched: wave w loads u in [w*16,w*16+16) -> polls slice w>>1.
// ---------------------------------------------------------------------------
__global__ __attribute__((amdgpu_flat_work_group_size(1024, 1024),
                          amdgpu_waves_per_eu(4, 4)))
void encoder_kernel(const float* __restrict__ x,
                    const float* __restrict__ Wf_k, const float* __restrict__ Wf_r,
                    const float* __restrict__ bf,
                    const float* __restrict__ Wb_k, const float* __restrict__ Wb_r,
                    const float* __restrict__ bb,
                    float* __restrict__ enc, float* __restrict__ h_ex,
                    int* __restrict__ flags)
{
    const int bid  = blockIdx.x;
    const int dir  = bid >> 7;
    const int tile = (bid >> 3) & 15;
    const int jsl  = bid & 7;
    const int grp  = dir * 16 + tile;
    const int bg0  = tile * 8;
    const float* __restrict__ Wk   = dir ? Wb_k : Wf_k;
    const float* __restrict__ Wr   = dir ? Wb_r : Wf_r;
    const float* __restrict__ bias = dir ? bb : bf;
    const int tid  = threadIdx.x;
    const int wv   = tid >> 6;
    const int lane = tid & 63;
    const int g0 = ((lane >> 5) << 8) + jsl * 32 + (lane & 31);

    __shared__ float zp[16][8][128];                // 64 KB
    __shared__ float __align__(16) hPe[2][4][520];  // 16.6 KB (batch-paired)
    __shared__ float WkL[5][128];
    __shared__ float biasL[128];
    __shared__ unsigned char mL[8][SEQ];            // 4 KB
    __shared__ float xLe[8][8];

    // ---- one-time staging ----
    for (int i = tid; i < 2 * 4 * 520; i += 1024) ((float*)hPe)[i] = 0.0f;
    if (tid < 128) biasL[tid] = bias[((tid >> 5) << 8) + jsl * 32 + (tid & 31)];
    if (tid >= 128 && tid < 768) {
        int i = tid - 128, c = i >> 7, cl = i & 127;
        WkL[c][cl] = Wk[c * 1024 + ((cl >> 5) << 8) + jsl * 32 + (cl & 31)];
    }
    for (int i = tid; i < 8 * SEQ; i += 1024) {
        int b = i >> 9, tt = i & (SEQ - 1);
        mL[b][tt] = (x[((size_t)((bg0 + b) * CCH) * SEQ + tt) * 3 + 2] != 0.0f) ? 1 : 0;
    }
    // weights -> registers: rows 16*wv..+15, cols (g0, g0+512) as v2f pairs
    v2f wp[16];
    {
        const float* wbase = Wr + (size_t)(wv * 16) * 1024 + g0;
        #pragma unroll
        for (int r = 0; r < 16; ++r) {
            v2f w; w.x = wbase[(size_t)r * 1024]; w.y = wbase[(size_t)r * 1024 + 512];
            wp[r] = w;
        }
    }
    float creg = 0.0f;
    __syncthreads();

    for (int t = 0; t < SEQ; ++t) {
        const int cur = t & 1;
        const int ts = dir ? (SEQ - 1 - t) : t;
        if (t > 0) {
            // wave w loads u in [w*16, w*16+16) => produced by slice w>>1
            const int* fp = &flags[(grp * 8 + (wv >> 1)) * 32];
            if (lane == 0) {
                int guard = 0;
                while (aloadi(fp) < t && guard < (1 << 26)) {
                    __builtin_amdgcn_s_sleep(1); ++guard;
                }
            }
            int p = lane >> 4, u = wv * 16 + (lane & 15);
            const unsigned long long* hsrc = (const unsigned long long*)
                &h_ex[(size_t)(dir * 2 + ((t - 1) & 1)) * (BATCH * UNITS)];
            unsigned long long v = aloadu64(hsrc + (size_t)((bg0 >> 1) + p) * UNITS + u);
            *(unsigned long long*)&hPe[cur][p][u * 2] = v;
        }
        if (tid >= 960 && tid < 1000) {  // wave 15: x_t for the 8 batches
            int i = tid - 960, b = i / 5, c = i - b * 5;
            xLe[b][c] = x[((size_t)((bg0 + b) * CCH + c) * SEQ + ts) * 3];
        }
        __syncthreads();   // B1

        // z-core: 16 rows x 2 cols per lane, batch-paired pk FMA
        v2f acc0[4], acc1[4];
        #pragma unroll
        for (int p = 0; p < 4; ++p) { acc0[p] = (v2f){0.f, 0.f}; acc1[p] = (v2f){0.f, 0.f}; }
        #pragma unroll
        for (int q = 0; q < 8; ++q) {           // 2 rows per q
            v2f h[4][2];
            #pragma unroll
            for (int p = 0; p < 4; ++p) {
                float4 A = *(const float4*)&hPe[cur][p][(wv * 16 + q * 2) * 2];
                v2f h0; h0.x = A.x; h0.y = A.y;
                v2f h1; h1.x = A.z; h1.y = A.w;
                h[p][0] = h0; h[p][1] = h1;
            }
            #pragma unroll
            for (int r = 0; r < 2; ++r) {
                v2f w2 = wp[q * 2 + r];
                #pragma unroll
                for (int p = 0; p < 4; ++p) {
                    PK_LO(acc0[p], h[p][r], w2);
                    PK_HI(acc1[p], h[p][r], w2);
                }
            }
        }
        #pragma unroll
        for (int p = 0; p < 4; ++p) {
            zp[wv][2 * p][lane]          = acc0[p].x;
            zp[wv][2 * p + 1][lane]      = acc0[p].y;
            zp[wv][2 * p][64 + lane]     = acc1[p].x;
            zp[wv][2 * p + 1][64 + lane] = acc1[p].y;
        }
        __syncthreads();   // B2

        if (tid < 256) {   // gates + mask + publish
            int b = tid >> 5, u = tid & 31;
            float zi = biasL[u], zf = biasL[32 + u], zg = biasL[64 + u], zo = biasL[96 + u];
            #pragma unroll
            for (int s = 0; s < 16; ++s) {
                zi += zp[s][b][u];       zf += zp[s][b][32 + u];
                zg += zp[s][b][64 + u];  zo += zp[s][b][96 + u];
            }
            #pragma unroll
            for (int c = 0; c < 5; ++c) {
                float xv = xLe[b][c];
                zi = fmaf(xv, WkL[c][u], zi);      zf = fmaf(xv, WkL[c][32 + u], zf);
                zg = fmaf(xv, WkL[c][64 + u], zg); zo = fmaf(xv, WkL[c][96 + u], zo);
            }
            float cn = sigmoidf_(zf) * creg + sigmoidf_(zi) * tanhf_(zg);
            float hn = sigmoidf_(zo) * tanhf_(cn);
            float hprev = hPe[cur][b >> 1][(jsl * 32 + u) * 2 + (b & 1)];
            float h2 = mL[b][ts] ? hn : hprev;
            float c2 = mL[b][ts] ? cn : creg;
            creg = c2;
            astoref(&h_ex[(size_t)(dir * 2 + cur) * (BATCH * UNITS)
                          + ((size_t)((bg0 + b) >> 1) * UNITS + jsl * 32 + u) * 2 + (b & 1)], h2);
            enc[((size_t)(bg0 + b) * SEQ + ts) * RU + dir * UNITS + jsl * 32 + u] = h2;
        }
        __syncthreads();   // B3 (drains the h stores)
        if (tid == 0) astorei(&flags[(grp * 8 + jsl) * 32], t + 1);
    }
}

// ---------------------------------------------------------------------------
// Attention precompute (alpha constant over decoder time). One block/batch.
// ---------------------------------------------------------------------------
__global__ __launch_bounds__(256)
void attn_kernel(const float* __restrict__ enc,
                 const float* __restrict__ W_attn, const float* __restrict__ b_attn,
                 const float* __restrict__ W_dense, const float* __restrict__ b_dense,
                 const float* __restrict__ x,
                 float* __restrict__ attn_ws, float* __restrict__ hidden_ws,
                 float* __restrict__ xbuf, float* __restrict__ xconst)
{
    const int b = blockIdx.x;
    const int tid = threadIdx.x;
    const int lane = tid & 63;
    const int wv = tid >> 6;

    __shared__ float WeL[RU];
    __shared__ float scoresL[SEQ];
    __shared__ float red[256];
    __shared__ float attnL[RU];

    WeL[tid]       = W_attn[CCH + tid];
    WeL[tid + 256] = W_attn[CCH + tid + 256];
    __syncthreads();

    const float* __restrict__ encb = enc + (size_t)b * SEQ * RU;
    const float batt = b_attn[0];

    for (int s = wv; s < SEQ; s += 4) {
        const float* row = encb + (size_t)s * RU;
        float p = 0.0f;
        #pragma unroll
        for (int i = 0; i < 8; ++i) {
            int d = lane * 8 + i;
            p = fmaf(row[d], WeL[d], p);
        }
        #pragma unroll
        for (int o = 32; o; o >>= 1) p += __shfl_xor(p, o);
        if (lane == 0) scoresL[s] = p + batt;
    }
    __syncthreads();

    float m = fmaxf(scoresL[tid], scoresL[tid + 256]);
    red[tid] = m;
    __syncthreads();
    for (int st = 128; st; st >>= 1) {
        if (tid < st) red[tid] = fmaxf(red[tid], red[tid + st]);
        __syncthreads();
    }
    const float mx = red[0];
    __syncthreads();
    float e0 = __expf(scoresL[tid] - mx);
    float e1 = __expf(scoresL[tid + 256] - mx);
    red[tid] = e0 + e1;
    __syncthreads();
    for (int st = 128; st; st >>= 1) {
        if (tid < st) red[tid] += red[tid + st];
        __syncthreads();
    }
    const float sinv = 1.0f / red[0];
    __syncthreads();
    scoresL[tid]       = e0 * sinv;
    scoresL[tid + 256] = e1 * sinv;
    __syncthreads();

    float a0 = 0.0f, a1 = 0.0f;
    for (int s = 0; s < SEQ; ++s) {
        float al = scoresL[s];
        a0 = fmaf(al, encb[(size_t)s * RU + tid], a0);
        a1 = fmaf(al, encb[(size_t)s * RU + tid + 256], a1);
    }
    attn_ws[(size_t)b * RU + tid]       = a0;
    attn_ws[(size_t)b * RU + tid + 256] = a1;
    attnL[tid] = a0;
    attnL[tid + 256] = a1;
    hidden_ws[(size_t)b * RU + tid]       = encb[(size_t)(SEQ - 1) * RU + tid];
    hidden_ws[(size_t)b * RU + tid + 256] = encb[(size_t)(SEQ - 1) * RU + tid + 256];
    if (tid < CCH) xbuf[b * CCH + tid] = x[((size_t)(b * CCH + tid) * SEQ + 0) * 3];
    __syncthreads();

    if (tid < CCH) {
        float acc = b_dense[tid];
        for (int d = 0; d < RU; ++d)
            acc = fmaf(attnL[d], W_dense[(RU + d) * CCH + tid], acc);
        xconst[b * CCH + tid] = acc;
    }
}

// ---------------------------------------------------------------------------
// Decoder: 256 blocks = tile(16; 8 batches) x slice(16; 32 units).
// h batch-paired in LDS; weights (32 rows x 2 cols)/lane; pk-FMA core.
// Wave w loads u in [w*32,+32) -> polls slice w (matched). out after flag.
// ---------------------------------------------------------------------------
__global__ __attribute__((amdgpu_flat_work_group_size(1024, 1024),
                          amdgpu_waves_per_eu(4, 4)))
void decoder_kernel(const float* __restrict__ Wd_k, const float* __restrict__ Wd_r,
                    const float* __restrict__ bd,
                    const float* __restrict__ W_dense,
                    const float* __restrict__ attn_ws, const float* __restrict__ hidden_ws,
                    const float* __restrict__ xbuf, const float* __restrict__ xconst,
                    float* __restrict__ h_ex, int* __restrict__ flags,
                    float* __restrict__ out)
{
    const int bid  = blockIdx.x;
    const int tile = bid >> 4;
    const int jsl  = bid & 15;
    const int bg0  = tile * 8;
    const int tid  = threadIdx.x;
    const int wv   = tid >> 6;
    const int lane = tid & 63;
    const int g0 = ((lane >> 5) << 9) + jsl * 32 + (lane & 31);

    __shared__ float zp[16][8][128];                 // 64 KB
    __shared__ float __align__(16) hPd[2][4][1040];  // 33.3 KB (batch-paired)
    __shared__ float WdL[RU * CCH];                  // 10 KB
    __shared__ float WkL[5][128];                    // 2.5 KB
    __shared__ float biasL[128];
    __shared__ float attL[8][32];
    __shared__ float xL[8][8], xcL[8][8];

    // ---- one-time staging ----
    for (int i = tid; i < RU * CCH; i += 1024) WdL[i] = W_dense[i];
    if (tid < 128) biasL[tid] = bd[((tid >> 5) << 9) + jsl * 32 + (tid & 31)];
    if (tid >= 128 && tid < 768) {
        int i = tid - 128, c = i >> 7, cl = i & 127;
        WkL[c][cl] = Wd_k[c * 2048 + ((cl >> 5) << 9) + jsl * 32 + (cl & 31)];
    }
    if (tid < 256) {
        int b = tid >> 5, u = tid & 31;
        attL[b][u] = attn_ws[(size_t)(bg0 + b) * RU + jsl * 32 + u];
    }
    if (tid < 64) {
        int b = tid >> 3, c = tid & 7;
        if (c < 5) {
            xL[b][c]  = xbuf[(bg0 + b) * CCH + c];
            xcL[b][c] = xconst[(bg0 + b) * CCH + c];
        }
    }
    // t=0 h from hidden_ws into paired layout
    for (int e = tid; e < 2048; e += 1024) {
        int p = e >> 9, u = e & 511;
        hPd[0][p][u * 2]     = hidden_ws[(size_t)(bg0 + 2 * p) * RU + u];
        hPd[0][p][u * 2 + 1] = hidden_ws[(size_t)(bg0 + 2 * p + 1) * RU + u];
    }
    // weights -> registers: rows 32*wv..+31, cols (g0, g0+1024) as v2f pairs
    v2f wp[32];
    {
        const float* wbase = Wd_r + (size_t)(wv * 32) * 2048 + g0;
        #pragma unroll
        for (int r = 0; r < 32; ++r) {
            v2f w; w.x = wbase[(size_t)r * 2048]; w.y = wbase[(size_t)r * 2048 + 1024];
            wp[r] = w;
        }
    }
    __syncthreads();

    for (int t = 0; t < SEQ - 1; ++t) {
        const int cur = t & 1;
        if (t > 0) {
            // wave w loads u in [w*32,+32) => produced by slice w (matched)
            const int* fp = &flags[(tile * 16 + wv) * 32];
            if (lane == 0) {
                int guard = 0;
                while (aloadi(fp) < t && guard < (1 << 26)) {
                    __builtin_amdgcn_s_sleep(1); ++guard;
                }
            }
            int p = lane >> 4, u0 = wv * 32 + (lane & 15) * 2;
            const unsigned long long* hsrc = (const unsigned long long*)
                &h_ex[(size_t)((t - 1) & 1) * (BATCH * RU)];
            unsigned long long v0 = aloadu64(hsrc + (size_t)((bg0 >> 1) + p) * RU + u0);
            unsigned long long v1 = aloadu64(hsrc + (size_t)((bg0 >> 1) + p) * RU + u0 + 1);
            *(unsigned long long*)&hPd[cur][p][u0 * 2]       = v0;
            *(unsigned long long*)&hPd[cur][p][(u0 + 1) * 2] = v1;
        }
        __syncthreads();   // B1

        // x_t = xconst + h . W_dense[:512]  (40 wave-reduced items)
        if (t > 0) {
            for (int it = wv; it < 40; it += 16) {
                int bb = it / 5, c = it - bb * 5;
                const float* hb = &hPd[cur][bb >> 1][bb & 1];
                float p = 0.f;
                #pragma unroll
                for (int q = 0; q < 8; ++q) {
                    int uu = lane + (q << 6);
                    p = fmaf(hb[uu * 2], WdL[uu * CCH + c], p);
                }
                #pragma unroll
                for (int o = 32; o; o >>= 1) p += __shfl_xor(p, o);
                if (lane == 0) xL[bb][c] = p + xcL[bb][c];
            }
        }

        // z-core: 32 rows x 2 cols per lane, batch-paired pk FMA
        v2f acc0[4], acc1[4];
        #pragma unroll
        for (int p = 0; p < 4; ++p) { acc0[p] = (v2f){0.f, 0.f}; acc1[p] = (v2f){0.f, 0.f}; }
        #pragma unroll
        for (int q = 0; q < 16; ++q) {          // 2 rows per q
            v2f h[4][2];
            #pragma unroll
            for (int p = 0; p < 4; ++p) {
                float4 A = *(const float4*)&hPd[cur][p][(wv * 32 + q * 2) * 2];
                v2f h0; h0.x = A.x; h0.y = A.y;
                v2f h1; h1.x = A.z; h1.y = A.w;
                h[p][0] = h0; h[p][1] = h1;
            }
            #pragma unroll
            for (int r = 0; r < 2; ++r) {
                v2f w2 = wp[q * 2 + r];
                #pragma unroll
                for (int p = 0; p < 4; ++p) {
                    PK_LO(acc0[p], h[p][r], w2);
                    PK_HI(acc1[p], h[p][r], w2);
                }
            }
        }
        #pragma unroll
        for (int p = 0; p < 4; ++p) {
            zp[wv][2 * p][lane]          = acc0[p].x;
            zp[wv][2 * p + 1][lane]      = acc0[p].y;
            zp[wv][2 * p][64 + lane]     = acc1[p].x;
            zp[wv][2 * p + 1][64 + lane] = acc1[p].y;
        }
        __syncthreads();   // B2

        if (tid < 256) {   // gates + publish h (paired layout)
            int b = tid >> 5, u = tid & 31;
            float zi = biasL[u], zf = biasL[32 + u], zg = biasL[64 + u], zo = biasL[96 + u];
            #pragma unroll
            for (int s = 0; s < 16; ++s) {
                zi += zp[s][b][u];       zf += zp[s][b][32 + u];
                zg += zp[s][b][64 + u];  zo += zp[s][b][96 + u];
            }
            #pragma unroll
            for (int c = 0; c < 5; ++c) {
                float xv = xL[b][c];
                zi = fmaf(xv, WkL[c][u], zi);      zf = fmaf(xv, WkL[c][32 + u], zf);
                zg = fmaf(xv, WkL[c][64 + u], zg); zo = fmaf(xv, WkL[c][96 + u], zo);
            }
            float cn = sigmoidf_(zf) * attL[b][u] + sigmoidf_(zi) * tanhf_(zg);
            float hn = sigmoidf_(zo) * tanhf_(cn);
            astoref(&h_ex[(size_t)cur * (BATCH * RU)
                          + ((size_t)((bg0 + b) >> 1) * RU + jsl * 32 + u) * 2 + (b & 1)], hn);
        }
        __syncthreads();   // B3 (drains the h stores)
        if (tid == 0) astorei(&flags[(tile * 16 + jsl) * 32], t + 1);
        // out-write off the drain path (xL stable until after next B1)
        if (t > 0 && jsl == 0 && tid >= 256 && tid < 296) {
            int i = tid - 256, bb = i / 5, c = i - bb * 5;
            out[(size_t)((bg0 + bb) * CCH + c) * (SEQ - 1) + (t - 1)] = xL[bb][c];
        }
    }

    // ---- epilogue: t = 511 -> out[510] from h_511 ----
    {
        const int t = SEQ - 1;          // 511
        const int cur = t & 1;          // 1
        const int* fp = &flags[(tile * 16 + wv) * 32];
        if (lane == 0) {
            int guard = 0;
            while (aloadi(fp) < t && guard < (1 << 26)) {
                __builtin_amdgcn_s_sleep(1); ++guard;
            }
        }
        int p = lane >> 4, u0 = wv * 32 + (lane & 15) * 2;
        const unsigned long long* hsrc = (const unsigned long long*)
            &h_ex[(size_t)((t - 1) & 1) * (BATCH * RU)];
        unsigned long long v0 = aloadu64(hsrc + (size_t)((bg0 >> 1) + p) * RU + u0);
        unsigned long long v1 = aloadu64(hsrc + (size_t)((bg0 >> 1) + p) * RU + u0 + 1);
        *(unsigned long long*)&hPd[cur][p][u0 * 2]       = v0;
        *(unsigned long long*)&hPd[cur][p][(u0 + 1) * 2] = v1;
        __syncthreads();
        if (jsl == 0) {
            for (int it = wv; it < 40; it += 16) {
                int bb = it / 5, c = it - bb * 5;
                const float* hb = &hPd[cur][bb >> 1][bb & 1];
                float p2 = 0.f;
                #pragma unroll
                for (int q = 0; q < 8; ++q) {
                    int uu = lane + (q << 6);
                    p2 = fmaf(hb[uu * 2], WdL[uu * CCH + c], p2);
                }
                #pragma unroll
                for (int o = 32; o; o >>= 1) p2 += __shfl_xor(p2, o);
                if (lane == 0)
                    out[(size_t)((bg0 + bb) * CCH + c) * (SEQ - 1) + (t - 1)]
                        = p2 + xcL[bb][c];
            }
        }
    }
}

// ---------------------------------------------------------------------------
extern "C" void kernel_launch(void* const* d_in, const int* in_sizes, int n_in,
                              void* d_out, int out_size, void* d_ws, size_t ws_size,
                              hipStream_t stream)
{
    const float* x       = (const float*)d_in[0];
    const float* Wf_k    = (const float*)d_in[1];
    const float* Wf_r    = (const float*)d_in[2];
    const float* bf      = (const float*)d_in[3];
    const float* Wb_k    = (const float*)d_in[4];
    const float* Wb_r    = (const float*)d_in[5];
    const float* bb      = (const float*)d_in[6];
    const float* Wd_k    = (const float*)d_in[7];
    const float* Wd_r    = (const float*)d_in[8];
    const float* bd      = (const float*)d_in[9];
    const float* W_attn  = (const float*)d_in[10];
    const float* b_attn  = (const float*)d_in[11];
    const float* W_dense = (const float*)d_in[12];
    const float* b_dense = (const float*)d_in[13];
    float* out = (float*)d_out;

    float* ws = (float*)d_ws;
    // persistent (attn -> decoder) region after enc
    float* enc      = ws;                          // [0, ENC_N)
    float* attn_p   = ws + ENC_N;                  // 65536 floats
    float* hidden_p = ws + ENC_N + 65536;          // 65536 floats
    float* xbuf_p   = ws + ENC_N + 131072;         // 640
    float* xconst_p = ws + ENC_N + 131712;         // 640
    // encoder-phase overlays (dead before attn_kernel writes the same region)
    float* h_ex_e   = ws + ENC_N;                  // 4 x 64 x 256 x 2 = 131072 floats
    int*   flag_e   = (int*)(ws + ENC_N + 131072); // 32 grp x 8 x 32 = 8192 ints
    // decoder-phase overlays on dead enc region
    int*   flag_d   = (int*)ws;                    // 16 tile x 16 x 32 = 8192 ints
    float* h_ex_d   = ws + 8192;                   // 2 x 64 x 512 x 2 = 131072 floats

    hipMemsetAsync(flag_e, 0, 8192 * sizeof(int), stream);
    encoder_kernel<<<256, 1024, 0, stream>>>(x, Wf_k, Wf_r, bf, Wb_k, Wb_r, bb,
                                             enc, h_ex_e, flag_e);
    attn_kernel<<<BATCH, 256, 0, stream>>>(enc, W_attn, b_attn, W_dense, b_dense, x,
                                           attn_p, hidden_p, xbuf_p, xconst_p);
    hipMemsetAsync(flag_d, 0, 8192 * sizeof(int), stream);
    decoder_kernel<<<256, 1024, 0, stream>>>(Wd_k, Wd_r, bd, W_dense,
                                             attn_p, hidden_p, xbuf_p, xconst_p,
                                             h_ex_d, flag_d, out);
}